// Round 10
// baseline (904.304 us; speedup 1.0000x reference)
//
#include <hip/hip_runtime.h>
#include <hip/hip_bf16.h>
#include <math.h>

constexpr int NE = 400000;
constexpr int NN = 40000;
constexpr int CD = 64;
constexpr int NGRAPH = 64;
constexpr int SCAN_BLOCKS = (NN + 255) / 256;   // 157

// ---------------- fc1: x0 = relu(x @ fc1_w + b) ----------------
__global__ void k_fc1(const float* __restrict__ x,
                      const float* __restrict__ w,
                      const float* __restrict__ b,
                      float* __restrict__ out) {
    int i = blockIdx.x * 256 + threadIdx.x;
    if (i >= NN * CD) return;
    int n = i >> 6, c = i & 63;
    float acc = b[c];
    #pragma unroll
    for (int k = 0; k < 9; ++k)
        acc = fmaf(x[n * 9 + k], w[k * 64 + c], acc);
    out[i] = fmaxf(acc, 0.f);
}

// ---------------- edge counts ----------------
__global__ void k_count(const int* __restrict__ ei, int* __restrict__ cnt) {
    int e = blockIdx.x * 256 + threadIdx.x;
    if (e >= NE) return;
    atomicAdd(&cnt[ei[e]], 1);
}

// ---------------- parallel scan, phase 1: per-block partial sums ----------------
__global__ void k_scan_part(const int* __restrict__ cnt, int* __restrict__ partials) {
    __shared__ int red[256];
    const int tid = threadIdx.x;
    const int i = blockIdx.x * 256 + tid;
    red[tid] = (i < NN) ? cnt[i] : 0;
    __syncthreads();
    for (int s = 128; s > 0; s >>= 1) {
        if (tid < s) red[tid] += red[tid + s];
        __syncthreads();
    }
    if (tid == 0) partials[blockIdx.x] = red[0];
}

// ---------------- phase 2: single-block scan of partials (nblk <= 256) ----------------
__global__ void k_scan_mid(const int* __restrict__ partials, int* __restrict__ offs, int nblk) {
    __shared__ int part[256];
    const int tid = threadIdx.x;
    const int v = (tid < nblk) ? partials[tid] : 0;
    part[tid] = v;
    __syncthreads();
    for (int off = 1; off < 256; off <<= 1) {
        int t = (tid >= off) ? part[tid - off] : 0;
        __syncthreads();
        part[tid] += t;
        __syncthreads();
    }
    if (tid < nblk) offs[tid] = part[tid] - v;   // exclusive
}

// ---------------- phase 3: in-block exclusive scan + base -> row_start, cursor ----------------
__global__ void k_scan_fill(const int* __restrict__ cnt, const int* __restrict__ offs,
                            int* __restrict__ row_start, int* __restrict__ cursor) {
    __shared__ int part[256];
    const int tid = threadIdx.x;
    const int i = blockIdx.x * 256 + tid;
    const int v = (i < NN) ? cnt[i] : 0;
    part[tid] = v;
    __syncthreads();
    for (int off = 1; off < 256; off <<= 1) {
        int t = (tid >= off) ? part[tid - off] : 0;
        __syncthreads();
        part[tid] += t;
        __syncthreads();
    }
    const int excl = part[tid] - v + offs[blockIdx.x];
    if (i < NN) { row_start[i] = excl; cursor[i] = excl; }
    if (i == NN - 1) row_start[NN] = NE;
}

// ---------------- scatter edge ids into CSR order ----------------
__global__ void k_scatter(const int* __restrict__ ei, int* __restrict__ cursor,
                          int* __restrict__ perm) {
    int e = blockIdx.x * 256 + threadIdx.x;
    if (e >= NE) return;
    int pos = atomicAdd(&cursor[ei[e]], 1);
    perm[pos] = e;
}

// ---------------- node projection, split output:
// Pi[n][0:64]  = bf + x@Wf_top   (row-side f)
// Pi[n][64:128]= bs + x@Ws_top   (row-side s)
// Pj[n][c] = (x@Wf_bot[c], x@Ws_bot[c])  as float2  (col-side, gathered)
__global__ void k_proj(const float* __restrict__ x,
                       const float* __restrict__ wf, const float* __restrict__ bfp,
                       const float* __restrict__ wsp, const float* __restrict__ bsp,
                       float* __restrict__ Pi, float* __restrict__ Pjf) {
    __shared__ float xs[8][64];
    const int tid = threadIdx.x;
    const int n0 = blockIdx.x * 8;
    for (int i = tid; i < 512; i += 256)
        xs[i >> 6][i & 63] = x[(size_t)(n0 + (i >> 6)) * 64 + (i & 63)];
    __syncthreads();
    const int q = tid >> 6, c = tid & 63;
    const float* __restrict__ wp = ((q & 2) ? wsp : wf) + ((q & 1) ? 64 * 64 : 0) + c;
    const float bias = (q == 0) ? bfp[c] : (q == 2 ? bsp[c] : 0.f);
    float acc[8];
    #pragma unroll
    for (int g = 0; g < 8; ++g) acc[g] = bias;
    for (int k = 0; k < 64; ++k) {
        const float wv = wp[k * 64];
        #pragma unroll
        for (int g = 0; g < 8; ++g) acc[g] = fmaf(xs[g][k], wv, acc[g]);
    }
    // q==0: Pi[c]; q==2: Pi[64+c]; q==1: Pj.x; q==3: Pj.y
    #pragma unroll
    for (int g = 0; g < 8; ++g) {
        const size_t n = n0 + g;
        if (q == 0)      Pi[n * 128 + c]          = acc[g];
        else if (q == 2) Pi[n * 128 + 64 + c]     = acc[g];
        else if (q == 1) Pjf[n * 128 + 2 * c]     = acc[g];
        else             Pjf[n * 128 + 2 * c + 1] = acc[g];
    }
}

// ---------------- CSR conv: 2 rows/wave, depth-1 prefetch each (4 gathers in flight) ----------------
__global__ void k_edge_csr(const int* __restrict__ ei, const float* __restrict__ ew,
                           const float* __restrict__ Pi, const float2* __restrict__ Pj,
                           const float* __restrict__ wfe, const float* __restrict__ wse,
                           const int* __restrict__ rs, const int* __restrict__ perm,
                           const float* __restrict__ xin, float* __restrict__ out) {
    const int c = threadIdx.x & 63;
    const int wv = (blockIdx.x * 256 + threadIdx.x) >> 6;
    const int r0 = wv * 2;
    if (r0 >= NN) return;
    const int r1 = r0 + 1;
    const float wf0 = wfe[c], wf1 = wfe[64 + c], wf2 = wfe[128 + c];
    const float ws0 = wse[c], ws1 = wse[64 + c], ws2 = wse[128 + c];
    const int b0 = rs[r0], d0 = rs[r0 + 1] - b0;
    const int b1 = rs[r1], d1 = rs[r1 + 1] - b1;
    const float pf0 = Pi[(size_t)r0 * 128 + c], ps0 = Pi[(size_t)r0 * 128 + 64 + c];
    const float pf1 = Pi[(size_t)r1 * 128 + c], ps1 = Pi[(size_t)r1 * 128 + 64 + c];
    float acc0 = 0.f, acc1 = 0.f;
    float2 J0n = make_float2(0.f, 0.f), J1n = make_float2(0.f, 0.f);
    float A0n = 0.f, B0n = 0.f, C0n = 0.f, A1n = 0.f, B1n = 0.f, C1n = 0.f;
    if (d0 > 0) {
        const int e = perm[b0]; const int cI = ei[NE + e];
        J0n = Pj[(size_t)cI * 64 + c];
        A0n = ew[3 * e]; B0n = ew[3 * e + 1]; C0n = ew[3 * e + 2];
    }
    if (d1 > 0) {
        const int e = perm[b1]; const int cI = ei[NE + e];
        J1n = Pj[(size_t)cI * 64 + c];
        A1n = ew[3 * e]; B1n = ew[3 * e + 1]; C1n = ew[3 * e + 2];
    }
    const int dmax = max(d0, d1);
    for (int i = 0; i < dmax; ++i) {
        const float2 J0 = J0n, J1 = J1n;
        const float A0 = A0n, B0 = B0n, C0 = C0n;
        const float A1 = A1n, B1 = B1n, C1 = C1n;
        if (i + 1 < d0) {
            const int e = perm[b0 + i + 1]; const int cI = ei[NE + e];
            J0n = Pj[(size_t)cI * 64 + c];
            A0n = ew[3 * e]; B0n = ew[3 * e + 1]; C0n = ew[3 * e + 2];
        }
        if (i + 1 < d1) {
            const int e = perm[b1 + i + 1]; const int cI = ei[NE + e];
            J1n = Pj[(size_t)cI * 64 + c];
            A1n = ew[3 * e]; B1n = ew[3 * e + 1]; C1n = ew[3 * e + 2];
        }
        if (i < d0) {
            const float af = pf0 + J0.x + A0 * wf0 + B0 * wf1 + C0 * wf2;
            const float as = ps0 + J0.y + A0 * ws0 + B0 * ws1 + C0 * ws2;
            const float sg = 1.f / (1.f + __expf(-af));
            const float sp = (as > 20.f) ? as : __logf(1.f + __expf(as));
            acc0 = fmaf(sg, sp, acc0);
        }
        if (i < d1) {
            const float af = pf1 + J1.x + A1 * wf0 + B1 * wf1 + C1 * wf2;
            const float as = ps1 + J1.y + A1 * ws0 + B1 * ws1 + C1 * ws2;
            const float sg = 1.f / (1.f + __expf(-af));
            const float sp = (as > 20.f) ? as : __logf(1.f + __expf(as));
            acc1 = fmaf(sg, sp, acc1);
        }
    }
    out[(size_t)r0 * 64 + c] = fmaxf(fmaf(acc0, 1.f / (float)max(d0, 1), xin[(size_t)r0 * 64 + c]), 0.f);
    out[(size_t)r1 * 64 + c] = fmaxf(fmaf(acc1, 1.f / (float)max(d1, 1), xin[(size_t)r1 * 64 + c]), 0.f);
}

// ---------------- fused GRU: h = GRU(m, h), weights from L2 ----------------
__global__ void k_gru_fused(const float* __restrict__ m, float* __restrict__ h,
                            const float* __restrict__ wih, const float* __restrict__ bih,
                            const float* __restrict__ whh, const float* __restrict__ bhh) {
    __shared__ float ms[32 * 65], hs[32 * 65];
    const int tid = threadIdx.x;
    const int n0 = blockIdx.x * 32;
    for (int i = tid; i < 2048; i += 256) {
        ms[(i >> 6) * 65 + (i & 63)] = m[(size_t)n0 * 64 + i];
        hs[(i >> 6) * 65 + (i & 63)] = h[(size_t)n0 * 64 + i];
    }
    __syncthreads();
    const int c = tid & 63, tg = tid >> 6;
    float ir[8], iz[8], inn[8], hr[8], hz[8], hn[8];
    #pragma unroll
    for (int j = 0; j < 8; ++j) { ir[j]=0.f; iz[j]=0.f; inn[j]=0.f; hr[j]=0.f; hz[j]=0.f; hn[j]=0.f; }
    for (int k = 0; k < 64; ++k) {
        const float wir = wih[k * 192 + c];
        const float wiz = wih[k * 192 + 64 + c];
        const float win = wih[k * 192 + 128 + c];
        const float whr = whh[k * 192 + c];
        const float whz = whh[k * 192 + 64 + c];
        const float whn = whh[k * 192 + 128 + c];
        #pragma unroll
        for (int j = 0; j < 8; ++j) {
            const float mk = ms[(j * 4 + tg) * 65 + k];
            const float hk = hs[(j * 4 + tg) * 65 + k];
            ir[j]  = fmaf(mk, wir, ir[j]);
            iz[j]  = fmaf(mk, wiz, iz[j]);
            inn[j] = fmaf(mk, win, inn[j]);
            hr[j]  = fmaf(hk, whr, hr[j]);
            hz[j]  = fmaf(hk, whz, hz[j]);
            hn[j]  = fmaf(hk, whn, hn[j]);
        }
    }
    const float bir = bih[c], biz = bih[64 + c], bin = bih[128 + c];
    const float bhr = bhh[c], bhz = bhh[64 + c], bhn = bhh[128 + c];
    #pragma unroll
    for (int j = 0; j < 8; ++j) {
        const int n = n0 + j * 4 + tg;
        const float r  = 1.f / (1.f + __expf(-((ir[j] + bir) + (hr[j] + bhr))));
        const float zg = 1.f / (1.f + __expf(-((iz[j] + biz) + (hz[j] + bhz))));
        const float ng = tanhf((inn[j] + bin) + r * (hn[j] + bhn));
        h[(size_t)n * 64 + c] = (1.f - zg) * ng + zg * hs[(j * 4 + tg) * 65 + c];
    }
}

// ---------------- first-node-per-graph indices (searchsorted) ----------------
__global__ void k_idx(const int* __restrict__ batch, int* __restrict__ idx) {
    int g = threadIdx.x;
    if (g >= NGRAPH) return;
    int lo = 0, hi = NN;
    while (lo < hi) {
        int mid = (lo + hi) >> 1;
        if (batch[mid] < g) lo = mid + 1; else hi = mid;
    }
    idx[g] = lo;
}

// ---------------- readout head: all weights/activations in LDS ----------------
__global__ void k_head(const float* __restrict__ h, const int* __restrict__ idx,
                       const float* __restrict__ fcsw, const float* __restrict__ fcsb,
                       const float* __restrict__ f2cw, const float* __restrict__ f2cb,
                       const float* __restrict__ f3cw, const float* __restrict__ f3cb,
                       const float* __restrict__ f2dw, const float* __restrict__ f2db,
                       const float* __restrict__ f3dw, const float* __restrict__ f3db,
                       float* __restrict__ out) {
    __shared__ float hsB[4096];  // hsel -> xgs
    __shared__ float waB[4096];  // fcsw -> xcs
    __shared__ float wbB[4096];  // f2cw -> xds
    __shared__ float wcB[4096];  // f2dw -> f3 weights
    const int tid = threadIdx.x;
    for (int i = tid; i < 4096; i += 256) {
        int g = i >> 6, k = i & 63;
        hsB[i] = h[(size_t)idx[g] * 64 + k];
        waB[i] = fcsw[i];
        wbB[i] = f2cw[i];
        wcB[i] = f2dw[i];
    }
    __syncthreads();
    float v[16];
    #pragma unroll
    for (int j = 0; j < 16; ++j) {
        const int i = j * 256 + tid, g = i >> 6, c = i & 63;
        float a = fcsb[c];
        for (int k = 0; k < 64; ++k) a = fmaf(hsB[g * 64 + k], waB[k * 64 + c], a);
        v[j] = fmaxf(a, 0.f);
    }
    __syncthreads();
    #pragma unroll
    for (int j = 0; j < 16; ++j) hsB[j * 256 + tid] = v[j];   // xgs
    __syncthreads();
    float vc[16], vd[16];
    #pragma unroll
    for (int j = 0; j < 16; ++j) {
        const int i = j * 256 + tid, g = i >> 6, c = i & 63;
        float a1 = f2cb[c], a2 = f2db[c];
        for (int k = 0; k < 64; ++k) {
            const float xv = hsB[g * 64 + k];
            a1 = fmaf(xv, wbB[k * 64 + c], a1);
            a2 = fmaf(xv, wcB[k * 64 + c], a2);
        }
        vc[j] = fmaxf(a1, 0.f);
        vd[j] = fmaxf(a2, 0.f);
    }
    __syncthreads();
    #pragma unroll
    for (int j = 0; j < 16; ++j) {
        waB[j * 256 + tid] = vc[j];   // xcs
        wbB[j * 256 + tid] = vd[j];   // xds
    }
    if (tid < 128) wcB[tid] = f3cw[tid];
    else           wcB[tid] = f3dw[tid - 128];
    __syncthreads();
    if (tid < 128) {
        int g = tid >> 1, j = tid & 1;
        float a = f3cb[j];
        for (int k = 0; k < 64; ++k) a = fmaf(waB[g * 64 + k], wcB[k * 2 + j], a);
        out[g * 2 + j] = 1.f / (1.f + expf(-a));
    } else {
        int t = tid - 128, g = t >> 1, j = t & 1;
        float a = f3db[j];
        for (int k = 0; k < 64; ++k) a = fmaf(wbB[g * 64 + k], wcB[128 + k * 2 + j], a);
        out[128 + g * 2 + j] = a;
    }
}

// ---------------- host launcher ----------------
extern "C" void kernel_launch(void* const* d_in, const int* in_sizes, int n_in,
                              void* d_out, int out_size, void* d_ws, size_t ws_size,
                              hipStream_t stream) {
    (void)in_sizes; (void)n_in; (void)out_size; (void)ws_size;
    const float* x    = (const float*)d_in[0];
    const int* ei1    = (const int*)d_in[1];
    const int* ei2    = (const int*)d_in[2];
    const float* w1   = (const float*)d_in[3];
    const float* w2   = (const float*)d_in[4];
    const int* batch  = (const int*)d_in[5];
    const float* fc1w = (const float*)d_in[6];
    const float* fc1b = (const float*)d_in[7];
    const float* lfw  = (const float*)d_in[8];
    const float* lfb  = (const float*)d_in[9];
    const float* lsw  = (const float*)d_in[10];
    const float* lsb  = (const float*)d_in[11];
    const float* wih  = (const float*)d_in[12];
    const float* bih  = (const float*)d_in[13];
    const float* whh  = (const float*)d_in[14];
    const float* bhh  = (const float*)d_in[15];
    const float* fcsw = (const float*)d_in[16];
    const float* fcsb = (const float*)d_in[17];
    const float* f2cw = (const float*)d_in[18];
    const float* f2cb = (const float*)d_in[19];
    const float* f3cw = (const float*)d_in[20];
    const float* f3cb = (const float*)d_in[21];
    const float* f2dw = (const float*)d_in[22];
    const float* f2db = (const float*)d_in[23];
    const float* f3dw = (const float*)d_in[24];
    const float* f3db = (const float*)d_in[25];

    char* ws = (char*)d_ws;
    size_t off = 0;
    auto alloc = [&](size_t bytes) { char* p = ws + off; off += (bytes + 255) & ~size_t(255); return p; };
    float* Pi    = (float*)alloc(size_t(NN) * 128 * 4);   // 20.5 MB
    float* Pjf   = (float*)alloc(size_t(NN) * 128 * 4);   // 20.5 MB (float2[64] per node)
    float* hbuf  = (float*)alloc(size_t(NN) * CD * 4);
    float* mbuf  = (float*)alloc(size_t(NN) * CD * 4);
    int*   cnt1  = (int*)alloc(size_t(NN) * 4);
    int*   cnt2  = (int*)alloc(size_t(NN) * 4);
    int*   rs1   = (int*)alloc(size_t(NN + 1) * 4);
    int*   rs2   = (int*)alloc(size_t(NN + 1) * 4);
    int*   cur1  = (int*)alloc(size_t(NN + 1) * 4);
    int*   cur2  = (int*)alloc(size_t(NN + 1) * 4);
    int*   perm1 = (int*)alloc(size_t(NE) * 4);
    int*   perm2 = (int*)alloc(size_t(NE) * 4);
    int*   part1 = (int*)alloc(256 * 4);
    int*   part2 = (int*)alloc(256 * 4);
    int*   offs1 = (int*)alloc(256 * 4);
    int*   offs2 = (int*)alloc(256 * 4);
    int*   idx   = (int*)alloc(256);

    const int NB_NC = (NN * CD + 255) / 256;
    const int NB_E  = (NE + 255) / 256;
    const int EDGE_BLOCKS = NN / 8;    // 5000: 4 waves/block, 2 rows/wave
    const int PROJ_BLOCKS = NN / 8;    // 5000
    const int GRU_BLOCKS  = NN / 32;   // 1250

    const float* lfe = lfw + 128 * 64;
    const float* lse = lsw + 128 * 64;

    // CSR build (parallel scan)
    hipMemsetAsync(cnt1, 0, size_t(NN) * 4, stream);
    hipMemsetAsync(cnt2, 0, size_t(NN) * 4, stream);
    k_count<<<NB_E, 256, 0, stream>>>(ei1, cnt1);
    k_count<<<NB_E, 256, 0, stream>>>(ei2, cnt2);
    k_scan_part<<<SCAN_BLOCKS, 256, 0, stream>>>(cnt1, part1);
    k_scan_part<<<SCAN_BLOCKS, 256, 0, stream>>>(cnt2, part2);
    k_scan_mid<<<1, 256, 0, stream>>>(part1, offs1, SCAN_BLOCKS);
    k_scan_mid<<<1, 256, 0, stream>>>(part2, offs2, SCAN_BLOCKS);
    k_scan_fill<<<SCAN_BLOCKS, 256, 0, stream>>>(cnt1, offs1, rs1, cur1);
    k_scan_fill<<<SCAN_BLOCKS, 256, 0, stream>>>(cnt2, offs2, rs2, cur2);
    k_scatter<<<NB_E, 256, 0, stream>>>(ei1, cur1, perm1);
    k_scatter<<<NB_E, 256, 0, stream>>>(ei2, cur2, perm2);

    k_fc1<<<NB_NC, 256, 0, stream>>>(x, fc1w, fc1b, hbuf);

    for (int it = 0; it < 3; ++it) {
        k_proj<<<PROJ_BLOCKS, 256, 0, stream>>>(hbuf, lfw, lfb, lsw, lsb, Pi, Pjf);
        k_edge_csr<<<EDGE_BLOCKS, 256, 0, stream>>>(ei2, w2, Pi, (const float2*)Pjf,
                                                    lfe, lse, rs2, perm2, hbuf, mbuf);
        k_proj<<<PROJ_BLOCKS, 256, 0, stream>>>(mbuf, lfw, lfb, lsw, lsb, Pi, Pjf);
        k_edge_csr<<<EDGE_BLOCKS, 256, 0, stream>>>(ei1, w1, Pi, (const float2*)Pjf,
                                                    lfe, lse, rs1, perm1, mbuf, mbuf);
        k_gru_fused<<<GRU_BLOCKS, 256, 0, stream>>>(mbuf, hbuf, wih, bih, whh, bhh);
    }

    k_idx<<<1, 64, 0, stream>>>(batch, idx);
    k_head<<<1, 256, 0, stream>>>(hbuf, idx, fcsw, fcsb, f2cw, f2cb, f3cw, f3cb,
                                  f2dw, f2db, f3dw, f3db, (float*)d_out);
}